// Round 14
// baseline (15.675 us; speedup 1.0000x reference)
//
#include <hip/hip_runtime.h>

// Problem constants (fixed by the reference)
#define NTOT 512   // N
#define NH   448   // N - K (identity head)
#define KK   64    // K (solved tail rows)
#define NL   30688 // strictly-lower entries in last K rows
#define DD   16    // domains

// z = F_d eps, F_d = (I-L)^{-1} S  <=>  (I-L) z = S eps.
// Head: z_j = eps_j + bias_sh. Tail r: y_r = s_r*eps_{448+r} + T_r.eps[0:448];
// z_tail = (I-U)^{-1} y (63-step wave chain).
// L_emb[dom] row m: T[m][0:448] at m*448+m(m-1)/2, then U[m][0:m] at +448.
// r14 = r13 (1024 blocks x 512 thr, LB(512,8) -> 32 waves/CU) minus eps_s
// (direct-global er[], r10-proven; barrier only for U_s) with 4-row phase-2
// batches + 10-shfl merged reduce (r4-verified): halves reduce-wait count.
__global__ __launch_bounds__(512, 8)
void fvae_fused(const float* __restrict__ eps,      // [B,512]
                const int*   __restrict__ dom_idx,  // [B]
                const float* __restrict__ L_emb,    // [16, NL]
                const float* __restrict__ S_emb,    // [16, 64]
                const float* __restrict__ bias_ns,  // [16, 64]
                const float* __restrict__ bias_sh,  // [448]
                float*       __restrict__ out)      // [B,512]
{
    const int b    = blockIdx.x;
    const int tid  = threadIdx.x;
    const int wave = tid >> 6;      // 0..7
    const int lane = tid & 63;

    __shared__ float y_s[KK];
    __shared__ float U_s[(KK * (KK - 1)) / 2];   // packed strictly-lower (7.9 KB)

    const int dom = dom_idx[b];
    const float* __restrict__ epsb = eps + (size_t)b * NTOT;
    float*       __restrict__ outb = out + (size_t)b * NTOT;

    if (dom == 0) {
        // L=0, S=I: out = eps + [bias_sh | bias_ns]; 128 quads
        if (tid < 128) {
            const float4 e = *(const float4*)(epsb + tid * 4);
            float4 bv;
            if (tid < 112) bv = *(const float4*)(bias_sh + tid * 4);
            else           bv = *(const float4*)(bias_ns + (tid - 112) * 4);
            float4 o; o.x = e.x + bv.x; o.y = e.y + bv.y;
            o.z = e.z + bv.z; o.w = e.w + bv.w;
            *(float4*)(outb + tid * 4) = o;
        }
        return;
    }

    const float* __restrict__ Ld = L_emb + (size_t)dom * NL;

    // ---- eps slice direct to registers (coalesced; r10-proven)
    float er[7];
    #pragma unroll
    for (int k = 0; k < 7; ++k) er[k] = epsb[lane + 64 * k];

    // ---- waves 1..7 stage packed U coalesced (r = wave + 7k covers 1..63)
    if (wave != 0) {
        for (int r = wave; r < KK; r += 7)
            if (lane < r)
                U_s[(r * (r - 1)) / 2 + lane] =
                    Ld[r * NH + (r * (r - 1)) / 2 + NH + lane];
    } else {
        // ---- wave 0: head write overlaps U staging (112 quads over 64 lanes)
        for (int q = lane; q < NH / 4; q += 64) {
            const float4 e  = *(const float4*)(epsb + q * 4);
            const float4 bs = *(const float4*)(bias_sh + q * 4);
            float4 o; o.x = e.x + bs.x; o.y = e.y + bs.y;
            o.z = e.z + bs.z; o.w = e.w + bs.w;
            *(float4*)(outb + q * 4) = o;
        }
    }
    __syncthreads();

    // ---- phase 2: wave owns rows [wave*8, +8), 2 batches of 4 rows
    #pragma unroll
    for (int bt = 0; bt < 2; ++bt) {
        const int r0 = wave * 8 + bt * 4;
        float a0, a1, a2, a3;
        {
            const float* __restrict__ T0 = Ld + (r0    ) * NH + ((r0    ) * (r0 - 1)) / 2;
            const float* __restrict__ T1 = Ld + (r0 + 1) * NH + ((r0 + 1) * (r0    )) / 2;
            const float* __restrict__ T2 = Ld + (r0 + 2) * NH + ((r0 + 2) * (r0 + 1)) / 2;
            const float* __restrict__ T3 = Ld + (r0 + 3) * NH + ((r0 + 3) * (r0 + 2)) / 2;
            a0 = T0[lane]*er[0] + T0[lane+64]*er[1] + T0[lane+128]*er[2]
               + T0[lane+192]*er[3] + T0[lane+256]*er[4] + T0[lane+320]*er[5]
               + T0[lane+384]*er[6];
            a1 = T1[lane]*er[0] + T1[lane+64]*er[1] + T1[lane+128]*er[2]
               + T1[lane+192]*er[3] + T1[lane+256]*er[4] + T1[lane+320]*er[5]
               + T1[lane+384]*er[6];
            a2 = T2[lane]*er[0] + T2[lane+64]*er[1] + T2[lane+128]*er[2]
               + T2[lane+192]*er[3] + T2[lane+256]*er[4] + T2[lane+320]*er[5]
               + T2[lane+384]*er[6];
            a3 = T3[lane]*er[0] + T3[lane+64]*er[1] + T3[lane+128]*er[2]
               + T3[lane+192]*er[3] + T3[lane+256]*er[4] + T3[lane+320]*er[5]
               + T3[lane+384]*er[6];
        }
        // merged butterfly reduce (r4-verified): lane g<4 holds sum of a_g
        a0 += __shfl_xor(a0, 1);  a1 += __shfl_xor(a1, 1);
        a2 += __shfl_xor(a2, 1);  a3 += __shfl_xor(a3, 1);
        float c0 = (lane & 1) ? a1 : a0;
        float c1 = (lane & 1) ? a3 : a2;
        c0 += __shfl_xor(c0, 2);  c1 += __shfl_xor(c1, 2);
        float dsum = (lane & 2) ? c1 : c0;
        dsum += __shfl_xor(dsum, 4);
        dsum += __shfl_xor(dsum, 8);
        dsum += __shfl_xor(dsum, 16);
        dsum += __shfl_xor(dsum, 32);
        if (lane < 4) {
            const int r = r0 + lane;
            y_s[r] = dsum + S_emb[dom * KK + r] * epsb[NH + r];
        }
    }
    __syncthreads();

    // ---- phase 3: wave 0; U_s read directly (addresses chain-independent)
    if (wave == 0) {
        const int m  = lane;
        const int tb = (m * (m - 1)) / 2;
        float z = y_s[m];
        #pragma unroll
        for (int r = 0; r < KK - 1; ++r) {
            const float u = (r < m) ? U_s[tb + r] : 0.f;
            z += u * __shfl(z, r);               // lane r's z final by step r
        }
        outb[NH + m] = z + bias_ns[dom * KK + m];
    }
}

extern "C" void kernel_launch(void* const* d_in, const int* in_sizes, int n_in,
                              void* d_out, int out_size, void* d_ws, size_t ws_size,
                              hipStream_t stream) {
    const float* eps     = (const float*)d_in[0];
    const int*   dom     = (const int*)  d_in[1];
    const float* L_emb   = (const float*)d_in[2];
    const float* S_emb   = (const float*)d_in[3];
    const float* bias_ns = (const float*)d_in[4];
    const float* bias_sh = (const float*)d_in[5];
    float* out = (float*)d_out;

    const int B = in_sizes[0] / NTOT;   // 1024
    fvae_fused<<<dim3(B), dim3(512), 0, stream>>>(eps, dom, L_emb, S_emb,
                                                  bias_ns, bias_sh, out);
}

// Round 15
// 15.047 us; speedup vs baseline: 1.0417x; 1.0417x over previous
//
#include <hip/hip_runtime.h>

// Problem constants (fixed by the reference)
#define NTOT 512   // N
#define NH   448   // N - K (identity head)
#define KK   64    // K (solved tail rows)
#define NL   30688 // strictly-lower entries in last K rows
#define DD   16    // domains

// z = F_d eps, F_d = (I-L)^{-1} S  <=>  (I-L) z = S eps.
// Head: z_j = eps_j + bias_sh. Tail r: y_r = s_r*eps_{448+r} + T_r.eps[0:448];
// z_tail = (I-U)^{-1} y (63-step wave chain).
// L_emb[dom] row m: T[m][0:448] at m*448+m(m-1)/2, then U[m][0:m] at +448.
// r15 = r14 with the FIRST BARRIER REMOVED: U_s is only read in phase 3,
// which runs after the y_s barrier -- that barrier already orders U_s writes.
// Removing it deletes one all-waves L2-latency sync from the critical path and
// lets er-loads, U-stage loads, and phase-2 T-loads issue as one deep
// independent VMEM batch (~23 outstanding loads/wave).
__global__ __launch_bounds__(512, 8)
void fvae_fused(const float* __restrict__ eps,      // [B,512]
                const int*   __restrict__ dom_idx,  // [B]
                const float* __restrict__ L_emb,    // [16, NL]
                const float* __restrict__ S_emb,    // [16, 64]
                const float* __restrict__ bias_ns,  // [16, 64]
                const float* __restrict__ bias_sh,  // [448]
                float*       __restrict__ out)      // [B,512]
{
    const int b    = blockIdx.x;
    const int tid  = threadIdx.x;
    const int wave = tid >> 6;      // 0..7
    const int lane = tid & 63;

    __shared__ float y_s[KK];
    __shared__ float U_s[(KK * (KK - 1)) / 2];   // packed strictly-lower (7.9 KB)

    const int dom = dom_idx[b];
    const float* __restrict__ epsb = eps + (size_t)b * NTOT;
    float*       __restrict__ outb = out + (size_t)b * NTOT;

    if (dom == 0) {
        // L=0, S=I: out = eps + [bias_sh | bias_ns]; 128 quads
        if (tid < 128) {
            const float4 e = *(const float4*)(epsb + tid * 4);
            float4 bv;
            if (tid < 112) bv = *(const float4*)(bias_sh + tid * 4);
            else           bv = *(const float4*)(bias_ns + (tid - 112) * 4);
            float4 o; o.x = e.x + bv.x; o.y = e.y + bv.y;
            o.z = e.z + bv.z; o.w = e.w + bv.w;
            *(float4*)(outb + tid * 4) = o;
        }
        return;
    }

    const float* __restrict__ Ld = L_emb + (size_t)dom * NL;

    // ---- eps slice direct to registers (coalesced; r10-proven)
    float er[7];
    #pragma unroll
    for (int k = 0; k < 7; ++k) er[k] = epsb[lane + 64 * k];

    // ---- waves 1..7 stage packed U coalesced (r = wave + 7k covers 1..63);
    //      wave 0 writes the head. NO barrier here: U_s is first read in
    //      phase 3, and the y_s barrier below already orders these writes.
    if (wave != 0) {
        for (int r = wave; r < KK; r += 7)
            if (lane < r)
                U_s[(r * (r - 1)) / 2 + lane] =
                    Ld[r * NH + (r * (r - 1)) / 2 + NH + lane];
    } else {
        for (int q = lane; q < NH / 4; q += 64) {
            const float4 e  = *(const float4*)(epsb + q * 4);
            const float4 bs = *(const float4*)(bias_sh + q * 4);
            float4 o; o.x = e.x + bs.x; o.y = e.y + bs.y;
            o.z = e.z + bs.z; o.w = e.w + bs.w;
            *(float4*)(outb + q * 4) = o;
        }
    }

    // ---- phase 2: wave owns rows [wave*8, +8), 2 batches of 4 rows
    #pragma unroll
    for (int bt = 0; bt < 2; ++bt) {
        const int r0 = wave * 8 + bt * 4;
        float a0, a1, a2, a3;
        {
            const float* __restrict__ T0 = Ld + (r0    ) * NH + ((r0    ) * (r0 - 1)) / 2;
            const float* __restrict__ T1 = Ld + (r0 + 1) * NH + ((r0 + 1) * (r0    )) / 2;
            const float* __restrict__ T2 = Ld + (r0 + 2) * NH + ((r0 + 2) * (r0 + 1)) / 2;
            const float* __restrict__ T3 = Ld + (r0 + 3) * NH + ((r0 + 3) * (r0 + 2)) / 2;
            a0 = T0[lane]*er[0] + T0[lane+64]*er[1] + T0[lane+128]*er[2]
               + T0[lane+192]*er[3] + T0[lane+256]*er[4] + T0[lane+320]*er[5]
               + T0[lane+384]*er[6];
            a1 = T1[lane]*er[0] + T1[lane+64]*er[1] + T1[lane+128]*er[2]
               + T1[lane+192]*er[3] + T1[lane+256]*er[4] + T1[lane+320]*er[5]
               + T1[lane+384]*er[6];
            a2 = T2[lane]*er[0] + T2[lane+64]*er[1] + T2[lane+128]*er[2]
               + T2[lane+192]*er[3] + T2[lane+256]*er[4] + T2[lane+320]*er[5]
               + T2[lane+384]*er[6];
            a3 = T3[lane]*er[0] + T3[lane+64]*er[1] + T3[lane+128]*er[2]
               + T3[lane+192]*er[3] + T3[lane+256]*er[4] + T3[lane+320]*er[5]
               + T3[lane+384]*er[6];
        }
        // merged butterfly reduce (r4-verified): lane g<4 holds sum of a_g
        a0 += __shfl_xor(a0, 1);  a1 += __shfl_xor(a1, 1);
        a2 += __shfl_xor(a2, 1);  a3 += __shfl_xor(a3, 1);
        float c0 = (lane & 1) ? a1 : a0;
        float c1 = (lane & 1) ? a3 : a2;
        c0 += __shfl_xor(c0, 2);  c1 += __shfl_xor(c1, 2);
        float dsum = (lane & 2) ? c1 : c0;
        dsum += __shfl_xor(dsum, 4);
        dsum += __shfl_xor(dsum, 8);
        dsum += __shfl_xor(dsum, 16);
        dsum += __shfl_xor(dsum, 32);
        if (lane < 4) {
            const int r = r0 + lane;
            y_s[r] = dsum + S_emb[dom * KK + r] * epsb[NH + r];
        }
    }
    __syncthreads();   // orders BOTH y_s and U_s writes before phase 3

    // ---- phase 3: wave 0; U_s read directly (addresses chain-independent)
    if (wave == 0) {
        const int m  = lane;
        const int tb = (m * (m - 1)) / 2;
        float z = y_s[m];
        #pragma unroll
        for (int r = 0; r < KK - 1; ++r) {
            const float u = (r < m) ? U_s[tb + r] : 0.f;
            z += u * __shfl(z, r);               // lane r's z final by step r
        }
        outb[NH + m] = z + bias_ns[dom * KK + m];
    }
}

extern "C" void kernel_launch(void* const* d_in, const int* in_sizes, int n_in,
                              void* d_out, int out_size, void* d_ws, size_t ws_size,
                              hipStream_t stream) {
    const float* eps     = (const float*)d_in[0];
    const int*   dom     = (const int*)  d_in[1];
    const float* L_emb   = (const float*)d_in[2];
    const float* S_emb   = (const float*)d_in[3];
    const float* bias_ns = (const float*)d_in[4];
    const float* bias_sh = (const float*)d_in[5];
    float* out = (float*)d_out;

    const int B = in_sizes[0] / NTOT;   // 1024
    fvae_fused<<<dim3(B), dim3(512), 0, stream>>>(eps, dom, L_emb, S_emb,
                                                  bias_ns, bias_sh, out);
}